// Round 1
// baseline (20.685 us; speedup 1.0000x reference)
//
#include <hip/hip_runtime.h>
#include <hip/hip_bf16.h>

// Problem constants (fixed by setup_inputs)
#define BB  64
#define NP  1024
#define NLA 128
#define NRR 256
#define NMM 32
#define HH  256
#define PFD 27
#define LFD 16
#define NAA 21

// Workspace layout (float offsets)
#define WS_PP 0          // partial protein feat sums: [256][27]
#define WS_LS 6912       // ligand per-batch feat sums: [64][16]
#define WS_AC 7936       // amino-acid counts (as float): [64][21]
#define WS_MF 9280       // per-motif feat sums: [2048][16]

__global__ __launch_bounds__(256) void reduce_kernel(
    const float* __restrict__ prot_feat,   // [B*NP][27]
    const float* __restrict__ lig_feat,    // [B*NL][16]
    const int*   __restrict__ amino_acid,  // [B*NR]
    float* __restrict__ ws)
{
  const int blk  = blockIdx.x;
  const int t    = threadIdx.x;
  const int lane = t & 63;
  const int wave = t >> 6;

  if (blk < 256) {
    // ---- protein feature partial sums: block handles 256 contiguous rows ----
    const int row = blk * 256 + t;
    const float* p = prot_feat + (size_t)row * PFD;
    float acc[PFD];
#pragma unroll
    for (int f = 0; f < PFD; ++f) acc[f] = p[f];
    __shared__ float swp[4][PFD];
#pragma unroll
    for (int f = 0; f < PFD; ++f) {
      float v = acc[f];
      v += __shfl_xor(v, 1);  v += __shfl_xor(v, 2);  v += __shfl_xor(v, 4);
      v += __shfl_xor(v, 8);  v += __shfl_xor(v, 16); v += __shfl_xor(v, 32);
      if (lane == 0) swp[wave][f] = v;
    }
    __syncthreads();
    if (t < PFD)
      ws[WS_PP + blk * PFD + t] = swp[0][t] + swp[1][t] + swp[2][t] + swp[3][t];
  } else if (blk < 288) {
    // ---- ligand: per-motif sums (groups of 4 lanes) + per-batch sums ----
    const int bl = blk - 256;            // 0..31 ; covers atoms [bl*256, bl*256+256)
    const int a  = bl * 256 + t;         // global ligand atom; motif g = a/4
    const float4* p = (const float4*)(lig_feat + (size_t)a * LFD);
    const float4 q0 = p[0], q1 = p[1], q2 = p[2], q3 = p[3];
    float acc[LFD] = {q0.x,q0.y,q0.z,q0.w, q1.x,q1.y,q1.z,q1.w,
                      q2.x,q2.y,q2.z,q2.w, q3.x,q3.y,q3.z,q3.w};
    __shared__ float swl[4][LFD];
    const int g = (bl * 64) + (t >> 2);  // global motif id for this 4-lane group
#pragma unroll
    for (int f = 0; f < LFD; ++f) {
      float v = acc[f];
      v += __shfl_xor(v, 1);  v += __shfl_xor(v, 2);      // 4-atom motif sum
      if ((t & 3) == 0) ws[WS_MF + g * LFD + f] = v;
      v += __shfl_xor(v, 4);  v += __shfl_xor(v, 8);
      v += __shfl_xor(v, 16); v += __shfl_xor(v, 32);     // wave (64-atom) sum
      if (lane == 0) swl[wave][f] = v;
    }
    __syncthreads();
    // waves 0,1 cover batch 2*bl ; waves 2,3 cover batch 2*bl+1 (128 atoms each)
    if (t < 16)       ws[WS_LS + (2*bl)   * LFD + t]        = swl[0][t]    + swl[1][t];
    else if (t < 32)  ws[WS_LS + (2*bl+1) * LFD + (t - 16)] = swl[2][t-16] + swl[3][t-16];
  } else {
    // ---- amino-acid counts: one block per batch ----
    const int b = blk - 288;
    __shared__ int icnt[NAA];
    if (t < NAA) icnt[t] = 0;
    __syncthreads();
    const int aa = amino_acid[b * NRR + t];
    atomicAdd(&icnt[aa], 1);
    __syncthreads();
    if (t < NAA) ws[WS_AC + b * NAA + t] = (float)icnt[t];
  }
}

__global__ __launch_bounds__(256) void score_kernel(
    const float* __restrict__ ws,
    const int*   __restrict__ ligand_wids,
    const float* __restrict__ W_prot, const float* __restrict__ b_prot,
    const float* __restrict__ W_lig,  const float* __restrict__ b_lig,
    const float* __restrict__ emb_table, const float* __restrict__ residue_emb,
    const float* __restrict__ W_mlp,  const float* __restrict__ b_mlp,
    float* __restrict__ out)
{
  const int b    = blockIdx.x;
  const int t    = threadIdx.x;
  const int lane = t & 63;
  const int wave = t >> 6;

  __shared__ float spf[PFD], slf[LFD], scnt[NAA];
  __shared__ float smfs[NMM * LFD];     // 32 motifs x 16 feats for this batch
  __shared__ float swred[4];
  __shared__ float sbase;
  __shared__ float slog[NMM];
  __shared__ float sexp[NMM];

  if (t < PFD) {
    float s = 0.f;
#pragma unroll
    for (int j = 0; j < 4; ++j) s += ws[WS_PP + (4*b + j) * PFD + t];
    spf[t] = s;
  } else if (t >= 32 && t < 32 + LFD) {
    slf[t - 32] = ws[WS_LS + b * LFD + (t - 32)];
  } else if (t >= 64 && t < 64 + NAA) {
    scnt[t - 64] = ws[WS_AC + b * NAA + (t - 64)];
  }
  smfs[t]       = ws[WS_MF + b * (NMM * LFD) + t];
  smfs[t + 256] = ws[WS_MF + b * (NMM * LFD) + t + 256];
  __syncthreads();

  // per-channel pooled reps for channel h = t
  float prep = 1024.f * b_prot[t];
#pragma unroll
  for (int f = 0; f < PFD; ++f) prep += spf[f] * W_prot[f * HH + t];
  float lrep = 128.f * b_lig[t];
#pragma unroll
  for (int f = 0; f < LFD; ++f) lrep += slf[f] * W_lig[f * HH + t];
  float rrep = 0.f;
#pragma unroll
  for (int a = 0; a < NAA; ++a) rrep += scnt[a] * residue_emb[a * HH + t];

  // shared (per-batch) part of the logit: chunks 0,1,2 of W_mlp
  float s = prep * W_mlp[t] + rrep * W_mlp[HH + t] + lrep * W_mlp[2*HH + t];
  s += __shfl_xor(s, 1);  s += __shfl_xor(s, 2);  s += __shfl_xor(s, 4);
  s += __shfl_xor(s, 8);  s += __shfl_xor(s, 16); s += __shfl_xor(s, 32);
  if (lane == 0) swred[wave] = s;
  __syncthreads();
  if (t == 0) sbase = swred[0] + swred[1] + swred[2] + swred[3] + b_mlp[0];
  __syncthreads();

  // per-motif varying part: wave w handles motifs w*8 .. w*8+7
  for (int mm = 0; mm < 8; ++mm) {
    const int m = wave * 8 + mm;
    const int g = b * NMM + m;
    const int wid = ligand_wids[g];
    const float* mfs = &smfs[m * LFD];
    float acc = 0.f;
#pragma unroll
    for (int j = 0; j < 4; ++j) {
      const int h = lane + 64 * j;
      acc += emb_table[(size_t)wid * HH + h] * W_mlp[3*HH + h];
      float tok = 4.f * b_lig[h];
#pragma unroll
      for (int f = 0; f < LFD; ++f) tok += mfs[f] * W_lig[f * HH + h];
      acc += tok * W_mlp[4*HH + h];
    }
    acc += __shfl_xor(acc, 1);  acc += __shfl_xor(acc, 2);  acc += __shfl_xor(acc, 4);
    acc += __shfl_xor(acc, 8);  acc += __shfl_xor(acc, 16); acc += __shfl_xor(acc, 32);
    if (lane == 0) slog[m] = sbase + acc;
  }
  __syncthreads();

  // softmax over the 32 motifs (threads 0..31)
  if (t < NMM) {
    const float x = slog[t];
    float mx = x;
    for (int j = 0; j < NMM; ++j) mx = fmaxf(mx, slog[j]);
    sexp[t] = expf(x - mx);
  }
  __syncthreads();
  if (t < NMM) {
    float sum = 0.f;
    for (int j = 0; j < NMM; ++j) sum += sexp[j];
    slog[t] = sexp[t] / sum;          // reuse slog as the score array
  }
  __syncthreads();
  // full stable descending sort via rank (ties -> lower index first),
  // replicating jax.lax.top_k(scores, 32)
  if (t < NMM) {
    const float sc = slog[t];
    int rank = 0;
    for (int j = 0; j < NMM; ++j) {
      const float sj = slog[j];
      rank += (sj > sc) || (sj == sc && j < t);
    }
    out[b * NMM + rank] = sc;                       // vals
    out[BB * NMM + b * NMM + rank] = (float)t;      // idx (as float)
  }
}

extern "C" void kernel_launch(void* const* d_in, const int* in_sizes, int n_in,
                              void* d_out, int out_size, void* d_ws, size_t ws_size,
                              hipStream_t stream) {
  const float* prot_feat   = (const float*)d_in[1];
  const float* lig_feat    = (const float*)d_in[2];
  const int*   amino_acid  = (const int*)d_in[5];
  const int*   ligand_wids = (const int*)d_in[7];
  const float* W_prot      = (const float*)d_in[12];
  const float* b_prot      = (const float*)d_in[13];
  const float* W_lig       = (const float*)d_in[14];
  const float* b_lig       = (const float*)d_in[15];
  const float* emb_table   = (const float*)d_in[16];
  const float* residue_emb = (const float*)d_in[17];
  const float* W_mlp       = (const float*)d_in[18];
  const float* b_mlp       = (const float*)d_in[19];

  float* ws  = (float*)d_ws;
  float* out = (float*)d_out;

  reduce_kernel<<<352, 256, 0, stream>>>(prot_feat, lig_feat, amino_acid, ws);
  score_kernel<<<64, 256, 0, stream>>>(ws, ligand_wids, W_prot, b_prot, W_lig, b_lig,
                                       emb_table, residue_emb, W_mlp, b_mlp, out);
}

// Round 2
// 11.241 us; speedup vs baseline: 1.8401x; 1.8401x over previous
//
#include <hip/hip_runtime.h>
#include <hip/hip_bf16.h>

// Problem constants (fixed by setup_inputs)
#define BB  64      // batches
#define NMM 32      // motifs per batch
#define HH  256     // hidden
#define LFD 16      // ligand feature dim
#define NLA 128     // ligand atoms per batch (NMM*4)

// Softmax over motifs (axis=1) is shift-invariant: protein_rep/residue_rep/
// ligand_rep/b_mlp/b_lig terms are constant per batch row and cancel exactly.
// Only emb_table[wid].w4 + motif_feat_sum.(W_lig@w5) survives.

__global__ __launch_bounds__(256) void score_kernel(
    const float* __restrict__ lig_feat,    // [B*128][16]
    const int*   __restrict__ wids,        // [B*32]
    const float* __restrict__ W_lig,       // [16][256]
    const float* __restrict__ emb_table,   // [501][256]
    const float* __restrict__ W_mlp,       // [1280][1]
    float* __restrict__ out)               // [64*32] vals, then [64*32] idx
{
  const int b    = blockIdx.x;
  const int t    = threadIdx.x;
  const int lane = t & 63;
  const int wave = t >> 6;

  __shared__ float semb[NMM * HH];   // 32 KB: this batch's 32 emb rows
  __shared__ float swl5[LFD];
  __shared__ float st5[NMM];
  __shared__ float slog[NMM];
  __shared__ float sexp[NMM];
  __shared__ float ssc[NMM];

  // ---- issue ligand-row loads early (t<128: row t of this batch) ----
  float4 q0, q1, q2, q3;
  if (t < NLA) {
    const float4* p = (const float4*)(lig_feat + (size_t)(b * NLA + t) * LFD);
    q0 = p[0]; q1 = p[1]; q2 = p[2]; q3 = p[3];
  }

  // ---- stage the 32 emb rows into LDS (parallel gather, one latency hit) ----
  {
    const int r = t >> 3;          // motif row 0..31
    const int c = t & 7;           // 8 threads per row, 8 float4 each
    const int wid = wids[b * NMM + r];
    const float4* er = (const float4*)(emb_table + (size_t)wid * HH);
    float4* sr = (float4*)(semb + r * HH);
#pragma unroll
    for (int k = 0; k < 8; ++k) sr[c + 8 * k] = er[c + 8 * k];
  }

  // ---- w4 chunk per lane ----
  float w4r[4];
#pragma unroll
  for (int j = 0; j < 4; ++j) w4r[j] = W_mlp[3 * HH + lane + 64 * j];

  // ---- wl5[f] = sum_h W_lig[f,h] * w5[h] : 16 threads per f ----
  {
    const int f = t >> 4, h0 = t & 15;
    float s = 0.f;
#pragma unroll
    for (int j = 0; j < 16; ++j)
      s += W_lig[f * HH + h0 + 16 * j] * W_mlp[4 * HH + h0 + 16 * j];
    s += __shfl_xor(s, 1); s += __shfl_xor(s, 2);
    s += __shfl_xor(s, 4); s += __shfl_xor(s, 8);
    if (h0 == 0) swl5[f] = s;
  }
  __syncthreads();

  // ---- motif feature sums (4-lane groups) + t5 = mfs . wl5 ----
  if (t < NLA) {
    float a[LFD] = {q0.x,q0.y,q0.z,q0.w, q1.x,q1.y,q1.z,q1.w,
                    q2.x,q2.y,q2.z,q2.w, q3.x,q3.y,q3.z,q3.w};
    float t5 = 0.f;
#pragma unroll
    for (int f = 0; f < LFD; ++f) {
      float v = a[f];
      v += __shfl_xor(v, 1); v += __shfl_xor(v, 2);   // 4-atom motif sum
      t5 += v * swl5[f];
    }
    if ((t & 3) == 0) st5[t >> 2] = t5;
  }

  // ---- e4[m] = emb_row[m] . w4 : wave w handles motifs w*8..w*8+7 ----
#pragma unroll
  for (int mm = 0; mm < 8; ++mm) {
    const int m = wave * 8 + mm;
    const float* sm = semb + m * HH;
    float s = sm[lane]       * w4r[0] + sm[lane + 64]  * w4r[1]
            + sm[lane + 128] * w4r[2] + sm[lane + 192] * w4r[3];
    s += __shfl_xor(s, 1);  s += __shfl_xor(s, 2);  s += __shfl_xor(s, 4);
    s += __shfl_xor(s, 8);  s += __shfl_xor(s, 16); s += __shfl_xor(s, 32);
    if (lane == 0) slog[m] = s;
  }
  __syncthreads();

  if (t < NMM) slog[t] += st5[t];
  __syncthreads();

  // ---- softmax over 32 motifs ----
  if (t < NMM) {
    float mx = slog[t];
    for (int j = 0; j < NMM; ++j) mx = fmaxf(mx, slog[j]);
    sexp[t] = expf(slog[t] - mx);
  }
  __syncthreads();
  if (t < NMM) {
    float sum = 0.f;
    for (int j = 0; j < NMM; ++j) sum += sexp[j];
    ssc[t] = sexp[t] / sum;
  }
  __syncthreads();

  // ---- full stable descending sort via rank (ties -> lower index first) ----
  if (t < NMM) {
    const float sc = ssc[t];
    int rank = 0;
    for (int j = 0; j < NMM; ++j) {
      const float sj = ssc[j];
      rank += (sj > sc) || (sj == sc && j < t);
    }
    out[b * NMM + rank] = sc;                        // vals
    out[BB * NMM + b * NMM + rank] = (float)t;       // idx (as float)
  }
}

extern "C" void kernel_launch(void* const* d_in, const int* in_sizes, int n_in,
                              void* d_out, int out_size, void* d_ws, size_t ws_size,
                              hipStream_t stream) {
  const float* lig_feat    = (const float*)d_in[2];
  const int*   ligand_wids = (const int*)d_in[7];
  const float* W_lig       = (const float*)d_in[14];
  const float* emb_table   = (const float*)d_in[16];
  const float* W_mlp       = (const float*)d_in[18];
  float* out = (float*)d_out;

  score_kernel<<<BB, 256, 0, stream>>>(lig_feat, ligand_wids, W_lig,
                                       emb_table, W_mlp, out);
}

// Round 3
// 10.369 us; speedup vs baseline: 1.9949x; 1.0842x over previous
//
#include <hip/hip_runtime.h>
#include <hip/hip_bf16.h>

// Problem constants (fixed by setup_inputs)
#define BB  64      // batches
#define NMM 32      // motifs per batch
#define HH  256     // hidden
#define LFD 16      // ligand feature dim
#define NLA 128     // ligand atoms per batch (NMM*4)

// Softmax over motifs (axis=1) is shift-invariant: protein_rep/residue_rep/
// ligand_rep/b_mlp/b_lig terms are constant per batch row and cancel exactly.
// logit[b,m] (up to a per-batch constant) =
//     emb_table[wid[b,m]] . w4  +  motif_feat_sum[b,m] . (W_lig @ w5)

__device__ __forceinline__ float dot4(float4 a, float4 b) {
  return a.x * b.x + a.y * b.y + a.z * b.z + a.w * b.w;
}

__global__ __launch_bounds__(256) void score_kernel(
    const float* __restrict__ lig_feat,    // [B*128][16]
    const int*   __restrict__ wids,        // [B*32]
    const float* __restrict__ W_lig,       // [16][256]
    const float* __restrict__ emb_table,   // [501][256]
    const float* __restrict__ W_mlp,       // [1280][1]
    float* __restrict__ out)               // [64*32] vals, then [64*32] idx
{
  const int b    = blockIdx.x;
  const int t    = threadIdx.x;
  const int lane = t & 63;
  const int wave = t >> 6;
  const int m    = wave * 8 + (lane >> 3); // motif this thread's 8-group handles
  const int c    = lane & 7;               // 32-channel chunk within the row

  __shared__ float swl5[LFD];
  __shared__ float slog[NMM];
  __shared__ float st5[NMM];

  // ---- dependent chain first: wid -> emb row chunk (straight to registers) ----
  const int wid = wids[b * NMM + m];
  const float4* er  = (const float4*)(emb_table + (size_t)wid * HH) + c * 8;
  const float4* w4p = (const float4*)(W_mlp + 3 * HH) + c * 8;
  float4 e0 = er[0], e1 = er[1], e2 = er[2], e3 = er[3],
         e4v = er[4], e5 = er[5], e6 = er[6], e7 = er[7];
  float4 w0 = w4p[0], w1 = w4p[1], w2 = w4p[2], w3 = w4p[3],
         w4v = w4p[4], w5v = w4p[5], w6 = w4p[6], w7 = w4p[7];

  // ---- ligand row load (t<128: atom t of this batch) ----
  float4 q0, q1, q2, q3;
  if (t < NLA) {
    const float4* p = (const float4*)(lig_feat + (size_t)(b * NLA + t) * LFD);
    q0 = p[0]; q1 = p[1]; q2 = p[2]; q3 = p[3];
  }

  // ---- swl5[f] = sum_h W_lig[f,h] * w5[h] : 16 threads per f ----
  {
    const int f = t >> 4, h0 = t & 15;
    float s = 0.f;
#pragma unroll
    for (int j = 0; j < 16; ++j)
      s += W_lig[f * HH + h0 + 16 * j] * W_mlp[4 * HH + h0 + 16 * j];
    s += __shfl_xor(s, 1); s += __shfl_xor(s, 2);
    s += __shfl_xor(s, 4); s += __shfl_xor(s, 8);
    if (h0 == 0) swl5[f] = s;
  }

  // ---- motif feature sums in registers (4-lane groups within waves 0,1) ----
  float ms[LFD];
  if (t < NLA) {
    float a[LFD] = {q0.x,q0.y,q0.z,q0.w, q1.x,q1.y,q1.z,q1.w,
                    q2.x,q2.y,q2.z,q2.w, q3.x,q3.y,q3.z,q3.w};
#pragma unroll
    for (int f = 0; f < LFD; ++f) {
      float v = a[f];
      v += __shfl_xor(v, 1); v += __shfl_xor(v, 2);   // 4-atom motif sum
      ms[f] = v;
    }
  }

  // ---- e4[m] = emb_row . w4 : partial over this lane's 32 channels ----
  {
    float s = dot4(e0, w0) + dot4(e1, w1) + dot4(e2, w2) + dot4(e3, w3)
            + dot4(e4v, w4v) + dot4(e5, w5v) + dot4(e6, w6) + dot4(e7, w7);
    s += __shfl_xor(s, 1); s += __shfl_xor(s, 2); s += __shfl_xor(s, 4);
    if (c == 0) slog[m] = s;
  }
  __syncthreads();   // swl5 + slog visible

  // ---- t5[m] = motif_feat_sum . swl5 ----
  if (t < NLA) {
    float t5 = 0.f;
#pragma unroll
    for (int f = 0; f < LFD; ++f) t5 += ms[f] * swl5[f];
    if ((t & 3) == 0) st5[t >> 2] = t5;
  }
  __syncthreads();   // st5 visible

  // ---- softmax + full stable descending rank, entirely in wave 0 ----
  if (t < NMM) {
    const float x = slog[t] + st5[t];
    float mx = x;
    mx = fmaxf(mx, __shfl_xor(mx, 1));
    mx = fmaxf(mx, __shfl_xor(mx, 2));
    mx = fmaxf(mx, __shfl_xor(mx, 4));
    mx = fmaxf(mx, __shfl_xor(mx, 8));
    mx = fmaxf(mx, __shfl_xor(mx, 16));
    const float ex = expf(x - mx);
    float sum = ex;
    sum += __shfl_xor(sum, 1); sum += __shfl_xor(sum, 2);
    sum += __shfl_xor(sum, 4); sum += __shfl_xor(sum, 8);
    sum += __shfl_xor(sum, 16);
    const float sc = ex / sum;
    int rank = 0;
#pragma unroll
    for (int j = 0; j < NMM; ++j) {
      const float sj = __shfl(sc, j);
      rank += (sj > sc) || (sj == sc && j < t);
    }
    out[b * NMM + rank] = sc;                        // vals
    out[BB * NMM + b * NMM + rank] = (float)t;       // idx (as float)
  }
}

extern "C" void kernel_launch(void* const* d_in, const int* in_sizes, int n_in,
                              void* d_out, int out_size, void* d_ws, size_t ws_size,
                              hipStream_t stream) {
  const float* lig_feat    = (const float*)d_in[2];
  const int*   ligand_wids = (const int*)d_in[7];
  const float* W_lig       = (const float*)d_in[14];
  const float* emb_table   = (const float*)d_in[16];
  const float* W_mlp       = (const float*)d_in[18];
  float* out = (float*)d_out;

  score_kernel<<<BB, 256, 0, stream>>>(lig_feat, ligand_wids, W_lig,
                                       emb_table, W_mlp, out);
}